// Round 11
// baseline (241.424 us; speedup 1.0000x reference)
//
#include <hip/hip_runtime.h>
#include <hip/hip_fp16.h>
#include <cmath>

#define NEG 0.2f

typedef __attribute__((ext_vector_type(8))) short short8;
typedef __attribute__((ext_vector_type(4))) float f32x4;
typedef __fp16 half2_t __attribute__((ext_vector_type(2)));

__device__ __forceinline__ float leaky(float v){ return v > 0.f ? v : NEG * v; }

__device__ __forceinline__ short bf16_rne(float f){
    unsigned u = __float_as_uint(f);
    unsigned r = u + 0x7fffu + ((u >> 16) & 1u);
    return (short)(r >> 16);
}
__device__ __forceinline__ float bf16_to_f(short s){
    return __uint_as_float(((unsigned)(unsigned short)s) << 16);
}
__device__ __forceinline__ half2_t bc16(unsigned u){ return __builtin_bit_cast(half2_t, u); }
__device__ __forceinline__ unsigned packh2(float a, float b){
    __half ha = __float2half(a), hb = __float2half(b);   // RNE
    return (unsigned)__builtin_bit_cast(unsigned short, ha)
         | ((unsigned)__builtin_bit_cast(unsigned short, hb) << 16);
}

// block-wide exclusive scan of one int per thread (256 threads)
__device__ __forceinline__ int block_excl_scan(int v, int* ws4){
    int tid = threadIdx.x, lane = tid & 63, wv = tid >> 6;
    int incl = v;
    #pragma unroll
    for (int off = 1; off < 64; off <<= 1){
        int t = __shfl_up(incl, off);
        if (lane >= off) incl += t;
    }
    if (lane == 63) ws4[wv] = incl;
    __syncthreads();
    int add = 0;
    for (int w = 0; w < wv; ++w) add += ws4[w];
    return incl - v + add;
}

// ---------------- prep (+ edge histogram + xp pack/alpha blocks) ----------------
// AGGREGATE-FIRST (r9, verified): gathers act on RAW features; dense GEMMs after.
// r10: xp stored fp16 [N][32] (64B rows, half of r9's f32) and the pack+alpha
// phase is fused here (hat1 recomputed per pack block — 14K flops, trivial).

__global__ __launch_bounds__(256) void prep_hist_kernel(
    const float* __restrict__ W1, const float* __restrict__ W2,
    const float* __restrict__ Ws1, const float* __restrict__ bs1,
    const float* __restrict__ donor,
    const float* __restrict__ as1, const float* __restrict__ ad1,
    const float* __restrict__ as2, const float* __restrict__ ad2,
    const float* __restrict__ x,
    short* __restrict__ w1p, short* __restrict__ w2p,
    short* __restrict__ s1hi, short* __restrict__ s1lo, float* __restrict__ d1p,
    float* __restrict__ hat2s, float* __restrict__ hat2d,
    __half* __restrict__ xp, float* __restrict__ asrc, float* __restrict__ adst,
    const int* __restrict__ ei, int E, int N, int NB, int* __restrict__ bucket_cnt,
    int hblk, int XBP)
{
    int b = (int)blockIdx.x;
    if (b < 256){
        int t = b * 256 + threadIdx.x;
        int T = 256 * 256;
        for (int i = t; i < 64 * 136; i += T){
            int c = i / 136, kk = i % 136; short v = 0;
            if (kk < 128){ int h = kk >> 5, k = kk & 31;
                if (k < 27) v = bf16_rne(W1[(size_t)k * 256 + h * 64 + c] * 0.25f); }
            w1p[i] = v;
        }
        for (int i = t; i < 64 * 264; i += T){
            int c = i / 264, kk = i % 264; short v = 0;
            if (kk < 256){ int h = kk >> 6, k = kk & 63;
                v = bf16_rne(W2[(size_t)k * 256 + h * 64 + c] * 0.25f); }
            w2p[i] = v;
        }
        for (int i = t; i < 64 * 72; i += T){
            int nn = i / 72, k = i % 72;
            float v = (k < 64) ? Ws1[(size_t)k * 64 + nn] : 0.f;
            short hi = bf16_rne(v);
            s1hi[i] = hi; s1lo[i] = bf16_rne(v - bf16_to_f(hi));
        }
        if (t < 64){
            float s = bs1[t];
            for (int k = 0; k < 32; ++k) s = fmaf(donor[k], Ws1[(size_t)(64 + k) * 64 + t], s);
            d1p[t] = s;
        }
        if (t < 256){
            int h = t >> 6, k = t & 63;
            float s = 0.f, d = 0.f;
            for (int c = 0; c < 64; ++c){
                float w = W2[(size_t)k * 256 + h * 64 + c];
                s = fmaf(w, as2[h * 64 + c], s);
                d = fmaf(w, ad2[h * 64 + c], d);
            }
            hat2s[t] = s; hat2d[t] = d;
        }
    } else if (b < 256 + hblk){
        __shared__ int lh[256];
        int tid = threadIdx.x;
        int ET = E + N;
        int ebase = (b - 256) * 2048;
        lh[tid] = 0;
        __syncthreads();
        #pragma unroll
        for (int j = 0; j < 8; ++j){
            int e = ebase + j * 256 + tid;
            if (e < ET){
                int d = (e < E) ? ei[E + e] : (e - E);
                atomicAdd(&lh[d >> 8], 1);
            }
        }
        __syncthreads();
        if (tid < NB && lh[tid]) atomicAdd(&bucket_cnt[tid], lh[tid]);
    } else {
        // pack + layer-1 alphas; hat1 computed locally (no cross-block dep)
        __shared__ float h1s[128], h1d[128];
        int tid = threadIdx.x;
        if (tid < 128){
            int h = tid >> 5, k = tid & 31;
            float s = 0.f, d = 0.f;
            if (k < 27)
                for (int c = 0; c < 64; ++c){
                    float w = W1[(size_t)k * 256 + h * 64 + c];
                    s = fmaf(w, as1[h * 64 + c], s);
                    d = fmaf(w, ad1[h * 64 + c], d);
                }
            h1s[tid] = s; h1d[tid] = d;
        }
        __syncthreads();
        int pb = b - 256 - hblk;
        int t0 = pb * 256 + tid, T = XBP * 256;
        for (int i = t0; i < N * 32; i += T){
            int nn = i >> 5, k = i & 31;
            xp[i] = __float2half((k < 27) ? x[(size_t)nn * 27 + k] : 0.f);
        }
        for (int nn = t0; nn < N; nn += T){
            float xr[27];
            #pragma unroll
            for (int k = 0; k < 27; ++k) xr[k] = x[(size_t)nn * 27 + k];
            #pragma unroll
            for (int h = 0; h < 4; ++h){
                float s = 0.f, d = 0.f;
                #pragma unroll
                for (int k = 0; k < 27; ++k){
                    s = fmaf(xr[k], h1s[h * 32 + k], s);
                    d = fmaf(xr[k], h1d[h * 32 + k], d);
                }
                asrc[nn * 4 + h] = s;
                adst[nn * 4 + h] = d;
            }
        }
    }
}

// ---------------- coarse scatter (self-scan, packed uint32 pairs) ----------------

__global__ __launch_bounds__(256) void coarse_scatter_kernel(
    const int* __restrict__ ei, int E, int N, int NB,
    const int* __restrict__ bucket_cnt, int* __restrict__ bucket_cursor,
    unsigned* __restrict__ pairs)
{
    __shared__ int ws4[4];
    __shared__ int gbase[256];
    __shared__ int lh[256];
    __shared__ int gb[256];
    int tid = threadIdx.x;
    int ET = E + N;
    {
        int v = (tid < NB) ? bucket_cnt[tid] : 0;
        gbase[tid] = block_excl_scan(v, ws4);
    }
    lh[tid] = 0;
    __syncthreads();
    int ebase = blockIdx.x * 2048;
    int d[8], s[8], r[8];
    #pragma unroll
    for (int j = 0; j < 8; ++j){
        int e = ebase + j * 256 + tid;
        d[j] = -1;
        if (e < ET){
            if (e < E){ s[j] = ei[e]; d[j] = ei[E + e]; } else { s[j] = d[j] = e - E; }
            r[j] = atomicAdd(&lh[d[j] >> 8], 1);
        }
    }
    __syncthreads();
    if (tid < NB && lh[tid]) gb[tid] = gbase[tid] + atomicAdd(&bucket_cursor[tid], lh[tid]);
    __syncthreads();
    #pragma unroll
    for (int j = 0; j < 8; ++j){
        if (d[j] >= 0)
            pairs[gb[d[j] >> 8] + r[j]] = ((unsigned)d[j] << 16) | (unsigned)s[j];
    }
}

// ---------------- fine sort (one 256-node bucket per block) ----------------

__global__ __launch_bounds__(256) void fine_sort_kernel(
    const unsigned* __restrict__ pairs, const int* __restrict__ bucket_cnt, int NB,
    int* __restrict__ colsrc, int* __restrict__ rowptr, int N, int ET)
{
    __shared__ int ws4f[4];
    __shared__ int sb[257];
    __shared__ int hist[256];
    __shared__ int cur[256];
    int b = (int)blockIdx.x;
    int tid = threadIdx.x;
    {
        int v = (tid < NB) ? bucket_cnt[tid] : 0;
        int excl = block_excl_scan(v, ws4f);
        sb[tid] = excl;
        if (tid == 255) sb[256] = excl + v;
    }
    hist[tid] = 0;
    __syncthreads();
    int base = sb[b], endb = sb[b + 1];
    int cnt = endb - base;
    int d0 = b << 8;
    for (int i = tid; i < cnt; i += 256){
        unsigned p = pairs[base + i];
        atomicAdd(&hist[(int)(p >> 16) - d0], 1);
    }
    __syncthreads();
    int v = hist[tid];
    int excl = block_excl_scan(v, ws4f);
    cur[tid] = excl;
    if (d0 + tid < N) rowptr[d0 + tid] = base + excl;
    if (b == 0 && tid == 0) rowptr[N] = ET;
    __syncthreads();
    for (int i = tid; i < cnt; i += 256){
        unsigned p = pairs[base + i];
        int r = atomicAdd(&cur[(int)(p >> 16) - d0], 1);
        colsrc[base + r] = (int)(p & 0xFFFFu);
    }
}

// ---------------- aggregation (r0 softmax structure; small payload rows) ----------------
// L=1: payload xp fp16[N][32] (64B rows). TWO edges per group-step: lanes 0-15
//      handle edge j, lanes 16-31 edge j+1, each lane a u32 (2 channels); halves
//      both gather bytes AND gather instruction count vs r9. Merge via shfl_xor(16).
//      G1 f32 [N][128] (kk=h*32+k).
// L=2: payload hmid fp16[N][64] (128B rows), lane owns 2 channels; G2 fp16 [N][256].

template<int L>
__global__ __launch_bounds__(256) void aggregate_kernel(
    const int* __restrict__ rowptr, const int* __restrict__ colsrc,
    const char* __restrict__ pay, const float* __restrict__ asrc,
    const float* __restrict__ adst, char* __restrict__ gout, int N)
{
    constexpr int RS = (L == 1) ? 64 : 128;    // payload row stride (bytes)
    int tid = threadIdx.x;
    int grp = tid >> 5;
    int lane32 = tid & 31;
    int n = blockIdx.x * 8 + grp;
    if (n >= N) return;
    int start = rowptr[n], end = rowptr[n + 1];
    int deg = end - start;
    const float4 ad = *(const float4*)(adst + (size_t)n * 4);

    int src0 = 0;
    float e0 = -1e30f, e1 = -1e30f, e2 = -1e30f, e3 = -1e30f;
    bool v0 = lane32 < deg;
    if (v0){
        src0 = colsrc[start + lane32];
        float4 as = *(const float4*)(asrc + (size_t)src0 * 4);
        e0 = leaky(as.x + ad.x); e1 = leaky(as.y + ad.y);
        e2 = leaky(as.z + ad.z); e3 = leaky(as.w + ad.w);
    }

    float m0, m1, m2, m3, i0, i1, i2, i3, p0, p1, p2, p3;
    if (deg <= 32){
        m0 = e0; m1 = e1; m2 = e2; m3 = e3;
        #pragma unroll
        for (int off = 1; off < 32; off <<= 1){
            m0 = fmaxf(m0, __shfl_xor(m0, off));
            m1 = fmaxf(m1, __shfl_xor(m1, off));
            m2 = fmaxf(m2, __shfl_xor(m2, off));
            m3 = fmaxf(m3, __shfl_xor(m3, off));
        }
        p0 = __expf(e0 - m0);
        p1 = __expf(e1 - m1);
        p2 = __expf(e2 - m2);
        p3 = __expf(e3 - m3);
        float t0 = p0, t1 = p1, t2 = p2, t3 = p3;
        #pragma unroll
        for (int off = 1; off < 32; off <<= 1){
            t0 += __shfl_xor(t0, off);
            t1 += __shfl_xor(t1, off);
            t2 += __shfl_xor(t2, off);
            t3 += __shfl_xor(t3, off);
        }
        i0 = 1.f / t0; i1 = 1.f / t1; i2 = 1.f / t2; i3 = 1.f / t3;
    } else {
        m0 = e0; m1 = e1; m2 = e2; m3 = e3;
        float t0 = v0 ? 1.f : 0.f, t1 = t0, t2 = t0, t3 = t0;
        for (int i = start + 32 + lane32; i < end; i += 32){
            int s = colsrc[i];
            float4 as = *(const float4*)(asrc + (size_t)s * 4);
            float e, nm;
            e = leaky(as.x + ad.x); nm = fmaxf(m0, e); t0 = t0 * __expf(m0 - nm) + __expf(e - nm); m0 = nm;
            e = leaky(as.y + ad.y); nm = fmaxf(m1, e); t1 = t1 * __expf(m1 - nm) + __expf(e - nm); m1 = nm;
            e = leaky(as.z + ad.z); nm = fmaxf(m2, e); t2 = t2 * __expf(m2 - nm) + __expf(e - nm); m2 = nm;
            e = leaky(as.w + ad.w); nm = fmaxf(m3, e); t3 = t3 * __expf(m3 - nm) + __expf(e - nm); m3 = nm;
        }
        #pragma unroll
        for (int off = 1; off < 32; off <<= 1){
            float om, os, nm;
            om = __shfl_xor(m0, off); os = __shfl_xor(t0, off);
            nm = fmaxf(m0, om); t0 = t0 * __expf(m0 - nm) + os * __expf(om - nm); m0 = nm;
            om = __shfl_xor(m1, off); os = __shfl_xor(t1, off);
            nm = fmaxf(m1, om); t1 = t1 * __expf(m1 - nm) + os * __expf(om - nm); m1 = nm;
            om = __shfl_xor(m2, off); os = __shfl_xor(t2, off);
            nm = fmaxf(m2, om); t2 = t2 * __expf(m2 - nm) + os * __expf(om - nm); m2 = nm;
            om = __shfl_xor(m3, off); os = __shfl_xor(t3, off);
            nm = fmaxf(m3, om); t3 = t3 * __expf(m3 - nm) + os * __expf(om - nm); m3 = nm;
        }
        i0 = 1.f / t0; i1 = 1.f / t1; i2 = 1.f / t2; i3 = 1.f / t3;
        p0 = __expf(e0 - m0); p1 = __expf(e1 - m1);
        p2 = __expf(e2 - m2); p3 = __expf(e3 - m3);
    }

    float accx[4] = {0.f, 0.f, 0.f, 0.f};
    float accy[4] = {0.f, 0.f, 0.f, 0.f};
    const int half = lane32 >> 4;
    const int boff = (L == 1) ? (lane32 & 15) * 4 : lane32 * 4;
    bool first = true;
    for (int base = start; base < end; base += 32){
        int cnt = end - base; if (cnt > 32) cnt = 32;
        float w0, w1, w2, w3; int off = 0;
        if (first){
            w0 = p0 * i0; w1 = p1 * i1; w2 = p2 * i2; w3 = p3 * i3;
            off = v0 ? src0 * RS : 0;
        } else {
            w0 = w1 = w2 = w3 = 0.f;
            if (lane32 < cnt){
                int s = colsrc[base + lane32];
                float4 as = *(const float4*)(asrc + (size_t)s * 4);
                w0 = __expf(leaky(as.x + ad.x) - m0) * i0;
                w1 = __expf(leaky(as.y + ad.y) - m1) * i1;
                w2 = __expf(leaky(as.z + ad.z) - m2) * i2;
                w3 = __expf(leaky(as.w + ad.w) - m3) * i3;
                off = s * RS;
            }
        }
        first = false;
        half2_t q01 = __builtin_amdgcn_cvt_pkrtz(w0, w1);
        half2_t q23 = __builtin_amdgcn_cvt_pkrtz(w2, w3);
        int wx = (int)__builtin_bit_cast(unsigned, q01);
        int wy = (int)__builtin_bit_cast(unsigned, q23);

        if (L == 1){
            for (int j = 0; j < cnt; j += 2){
                int jj = j + half;
                int sel = (jj < cnt) ? jj : 0;
                int o = __shfl(off, sel, 32);
                unsigned aw = (unsigned)__shfl(wx, sel, 32);
                unsigned bw = (unsigned)__shfl(wy, sel, 32);
                if (jj >= cnt){ aw = 0u; bw = 0u; }
                unsigned xv = *(const unsigned*)(pay + o + boff);
                half2_t xh = bc16(xv);
                float c0 = (float)xh[0], c1 = (float)xh[1];
                half2_t ah = bc16(aw), bh = bc16(bw);
                float f0 = (float)ah[0], f1 = (float)ah[1], f2 = (float)bh[0], f3 = (float)bh[1];
                accx[0] = fmaf(f0, c0, accx[0]); accy[0] = fmaf(f0, c1, accy[0]);
                accx[1] = fmaf(f1, c0, accx[1]); accy[1] = fmaf(f1, c1, accy[1]);
                accx[2] = fmaf(f2, c0, accx[2]); accy[2] = fmaf(f2, c1, accy[2]);
                accx[3] = fmaf(f3, c0, accx[3]); accy[3] = fmaf(f3, c1, accy[3]);
            }
        } else {
            for (int j = 0; j < cnt; ++j){
                int o = __shfl(off, j, 32);
                unsigned aw = (unsigned)__shfl(wx, j, 32);
                unsigned bw = (unsigned)__shfl(wy, j, 32);
                unsigned hv = *(const unsigned*)(pay + o + boff);
                half2_t hh = bc16(hv);
                float c0 = (float)hh[0], c1 = (float)hh[1];
                half2_t ah = bc16(aw), bh = bc16(bw);
                float f0 = (float)ah[0], f1 = (float)ah[1], f2 = (float)bh[0], f3 = (float)bh[1];
                accx[0] = fmaf(f0, c0, accx[0]); accy[0] = fmaf(f0, c1, accy[0]);
                accx[1] = fmaf(f1, c0, accx[1]); accy[1] = fmaf(f1, c1, accy[1]);
                accx[2] = fmaf(f2, c0, accx[2]); accy[2] = fmaf(f2, c1, accy[2]);
                accx[3] = fmaf(f3, c0, accx[3]); accy[3] = fmaf(f3, c1, accy[3]);
            }
        }
    }

    if (L == 1){
        #pragma unroll
        for (int h = 0; h < 4; ++h){
            accx[h] += __shfl_xor(accx[h], 16);
            accy[h] += __shfl_xor(accy[h], 16);
        }
        if (lane32 < 16){
            float* g = (float*)gout;
            #pragma unroll
            for (int h = 0; h < 4; ++h)
                *(float2*)(g + (size_t)n * 128 + h * 32 + 2 * lane32) =
                    make_float2(accx[h], accy[h]);
        }
    } else {
        #pragma unroll
        for (int h = 0; h < 4; ++h){
            unsigned u = packh2(accx[h], accy[h]);
            *(unsigned*)(gout + (size_t)n * 512 + h * 128 + lane32 * 4) = u;
        }
    }
}

// ---------------- t1post: hmid = elu(G1 @ W1p + b1), + layer-2 alphas ----------------

__global__ __launch_bounds__(256) void t1post_kernel(
    const float* __restrict__ G1, const short* __restrict__ w1p, const float* __restrict__ b1,
    const float* __restrict__ hat2s, const float* __restrict__ hat2d,
    __half* __restrict__ hm16, float* __restrict__ asrc, float* __restrict__ adst, int N)
{
    constexpr int WP = 136;
    __shared__ short wt[64 * WP];
    const int tid = threadIdx.x;
    const int n0 = blockIdx.x * 64;
    const int wv = tid >> 6, lane = tid & 63;
    const int quad = lane >> 4, ln = lane & 15;
    const int myrow = wv * 16 + ln;
    const int nme = n0 + myrow;

    {
        const short8* g = (const short8*)w1p;
        short8* l = (short8*)wt;
        for (int t = tid; t < 64 * WP / 8; t += 256) l[t] = g[t];
    }
    __syncthreads();

    f32x4 acc[4];
    #pragma unroll
    for (int i = 0; i < 4; ++i) acc[i] = (f32x4){0.f, 0.f, 0.f, 0.f};

    #pragma unroll
    for (int ks = 0; ks < 4; ++ks){
        const int k0 = ks * 32 + quad * 8;
        float4 f0 = make_float4(0.f, 0.f, 0.f, 0.f), f1 = f0;
        if (nme < N){
            const float* ap = G1 + (size_t)nme * 128 + k0;
            f0 = *(const float4*)ap;
            f1 = *(const float4*)(ap + 4);
        }
        float fa[8] = {f0.x, f0.y, f0.z, f0.w, f1.x, f1.y, f1.z, f1.w};
        short8 ahi, alo;
        #pragma unroll
        for (int e = 0; e < 8; ++e){
            short hi = bf16_rne(fa[e]);
            ahi[e] = hi;
            alo[e] = bf16_rne(fa[e] - bf16_to_f(hi));
        }
        #pragma unroll
        for (int nt = 0; nt < 4; ++nt){
            short8 bhi = *(const short8*)(wt + (nt * 16 + ln) * WP + k0);
            acc[nt] = __builtin_amdgcn_mfma_f32_16x16x32_bf16(ahi, bhi, acc[nt], 0, 0, 0);
            acc[nt] = __builtin_amdgcn_mfma_f32_16x16x32_bf16(alo, bhi, acc[nt], 0, 0, 0);
        }
    }

    float b1v[4], hs[4][4], hd[4][4];
    #pragma unroll
    for (int nt = 0; nt < 4; ++nt) b1v[nt] = b1[nt * 16 + ln];
    #pragma unroll
    for (int h = 0; h < 4; ++h)
        #pragma unroll
        for (int nt = 0; nt < 4; ++nt){
            hs[h][nt] = hat2s[h * 64 + nt * 16 + ln];
            hd[h][nt] = hat2d[h * 64 + nt * 16 + ln];
        }

    #pragma unroll
    for (int r = 0; r < 4; ++r){
        int n = n0 + wv * 16 + quad * 4 + r;
        float ev[4];
        #pragma unroll
        for (int nt = 0; nt < 4; ++nt){
            float v = acc[nt][r] + b1v[nt];
            v = (v > 0.f) ? v : expm1f(v);
            ev[nt] = v;
        }
        if (n < N){
            #pragma unroll
            for (int nt = 0; nt < 4; ++nt)
                hm16[(size_t)n * 64 + nt * 16 + ln] = __float2half(ev[nt]);
        }
        #pragma unroll
        for (int h = 0; h < 4; ++h){
            float ps = 0.f, pd = 0.f;
            #pragma unroll
            for (int nt = 0; nt < 4; ++nt){
                ps = fmaf(ev[nt], hs[h][nt], ps);
                pd = fmaf(ev[nt], hd[h][nt], pd);
            }
            #pragma unroll
            for (int off = 1; off < 16; off <<= 1){
                ps += __shfl_xor(ps, off);
                pd += __shfl_xor(pd, off);
            }
            if (ln == 0 && n < N){
                asrc[n * 4 + h] = ps;
                adst[n * 4 + h] = pd;
            }
        }
    }
}

// ---------------- t2post+scorer fused: elu(G2@W2p+b2) -> LDS -> scorer MFMA ----------------
// Deletes the hmid2 global round-trip (25.6MB) and one launch. LDS overlay:
// phase A uses wt[64*264]short (33.8KB); phase B reuses as hm[64][68]f32 (17.4KB)
// + whi/wlo (18.4KB) = 35.8KB peak.

__global__ __launch_bounds__(256) void t2post_scorer_kernel(
    const char* __restrict__ G2, const short* __restrict__ w2p, const float* __restrict__ b2,
    const short* __restrict__ s1hi, const short* __restrict__ s1lo,
    const float* __restrict__ d1p, const float* __restrict__ Ws2, const float* __restrict__ bs2,
    float* __restrict__ out, int N)
{
    constexpr int WP2 = 264;
    constexpr int WPS = 72;
    __shared__ __align__(16) char S[64 * 68 * 4 + 2 * 64 * WPS * 2];   // 35840 B
    const int tid = threadIdx.x;
    const int n0 = blockIdx.x * 64;
    const int wv = tid >> 6, lane = tid & 63;
    const int quad = lane >> 4, ln = lane & 15;
    const int myrow = wv * 16 + ln;
    const int nme = n0 + myrow;

    // ---- phase A: G2 @ W2p
    short* wt = (short*)S;
    {
        const short8* g = (const short8*)w2p;
        short8* l = (short8*)wt;
        for (int t = tid; t < 64 * WP2 / 8; t += 256) l[t] = g[t];
    }
    __syncthreads();

    f32x4 acc[4];
    #pragma unroll
    for (int i = 0; i < 4; ++i) acc[i] = (f32x4){0.f, 0.f, 0.f, 0.f};

    #pragma unroll
    for (int ks = 0; ks < 8; ++ks){
        const int k0 = ks * 32 + quad * 8;
        uint4 u = make_uint4(0u, 0u, 0u, 0u);
        if (nme < N)
            u = *(const uint4*)(G2 + (size_t)nme * 512 + (size_t)k0 * 2);
        half2_t h0 = bc16(u.x), h1 = bc16(u.y), h2 = bc16(u.z), h3 = bc16(u.w);
        float fa[8] = {(float)h0[0], (float)h0[1], (float)h1[0], (float)h1[1],
                       (float)h2[0], (float)h2[1], (float)h3[0], (float)h3[1]};
        short8 ahi, alo;
        #pragma unroll
        for (int e = 0; e < 8; ++e){
            short hi = bf16_rne(fa[e]);
            ahi[e] = hi;
            alo[e] = bf16_rne(fa[e] - bf16_to_f(hi));
        }
        #pragma unroll
        for (int nt = 0; nt < 4; ++nt){
            short8 bhi = *(const short8*)(wt + (nt * 16 + ln) * WP2 + k0);
            acc[nt] = __builtin_amdgcn_mfma_f32_16x16x32_bf16(ahi, bhi, acc[nt], 0, 0, 0);
            acc[nt] = __builtin_amdgcn_mfma_f32_16x16x32_bf16(alo, bhi, acc[nt], 0, 0, 0);
        }
    }

    float b2v[4];
    #pragma unroll
    for (int nt = 0; nt < 4; ++nt) b2v[nt] = b2[nt * 16 + ln];

    // ---- LDS overlay swap: wt no longer needed
    __syncthreads();
    float* hm  = (float*)S;                       // [64][68]
    short* whi = (short*)(S + 64 * 68 * 4);
    short* wlo = whi + 64 * WPS;

    #pragma unroll
    for (int r = 0; r < 4; ++r){
        int row = wv * 16 + quad * 4 + r;
        #pragma unroll
        for (int nt = 0; nt < 4; ++nt){
            float v = acc[nt][r] + b2v[nt];
            v = (v > 0.f) ? v : expm1f(v);
            hm[row * 68 + nt * 16 + ln] = v;
        }
    }
    {
        const short8* ghi = (const short8*)s1hi;
        const short8* glo = (const short8*)s1lo;
        short8* lhi = (short8*)whi;
        short8* llo = (short8*)wlo;
        for (int t = tid; t < 64 * WPS / 8; t += 256){ lhi[t] = ghi[t]; llo[t] = glo[t]; }
    }
    __syncthreads();

    // ---- phase B: scorer
    f32x4 acc2[4];
    #pragma unroll
    for (int i = 0; i < 4; ++i) acc2[i] = (f32x4){0.f, 0.f, 0.f, 0.f};

    #pragma unroll
    for (int ks = 0; ks < 2; ++ks){
        const int k0 = ks * 32 + quad * 8;
        short8 ahi, alo;
        #pragma unroll
        for (int e = 0; e < 8; ++e){
            float v = hm[myrow * 68 + k0 + e];
            short hi = bf16_rne(v);
            ahi[e] = hi;
            alo[e] = bf16_rne(v - bf16_to_f(hi));
        }
        #pragma unroll
        for (int nt = 0; nt < 4; ++nt){
            short8 bhi = *(const short8*)(whi + (nt * 16 + ln) * WPS + k0);
            short8 blo = *(const short8*)(wlo + (nt * 16 + ln) * WPS + k0);
            acc2[nt] = __builtin_amdgcn_mfma_f32_16x16x32_bf16(ahi, bhi, acc2[nt], 0, 0, 0);
            acc2[nt] = __builtin_amdgcn_mfma_f32_16x16x32_bf16(alo, bhi, acc2[nt], 0, 0, 0);
            acc2[nt] = __builtin_amdgcn_mfma_f32_16x16x32_bf16(ahi, blo, acc2[nt], 0, 0, 0);
        }
    }

    float d1v[4], w2v[4];
    #pragma unroll
    for (int nt = 0; nt < 4; ++nt){
        d1v[nt] = d1p[nt * 16 + ln];
        w2v[nt] = Ws2[nt * 16 + ln];
    }
    float bsv = bs2[0];
    #pragma unroll
    for (int r = 0; r < 4; ++r){
        float t = 0.f;
        #pragma unroll
        for (int nt = 0; nt < 4; ++nt)
            t = fmaf(fmaxf(acc2[nt][r] + d1v[nt], 0.f), w2v[nt], t);
        #pragma unroll
        for (int off = 1; off < 16; off <<= 1) t += __shfl_xor(t, off);
        if (ln == 0){
            int n = n0 + wv * 16 + quad * 4 + r;
            if (n < N) out[n] = t + bsv;
        }
    }
}

// ---------------- launch ----------------

extern "C" void kernel_launch(void* const* d_in, const int* in_sizes, int n_in,
                              void* d_out, int out_size, void* d_ws, size_t ws_size,
                              hipStream_t stream)
{
    const float* x    = (const float*)d_in[0];
    const int*   ei   = (const int*)  d_in[1];
    const float* donor= (const float*)d_in[2];
    const float* W1   = (const float*)d_in[3];
    const float* as1  = (const float*)d_in[4];
    const float* ad1  = (const float*)d_in[5];
    const float* b1   = (const float*)d_in[6];
    const float* W2   = (const float*)d_in[7];
    const float* as2  = (const float*)d_in[8];
    const float* ad2  = (const float*)d_in[9];
    const float* b2   = (const float*)d_in[10];
    const float* Ws1  = (const float*)d_in[11];
    const float* bs1  = (const float*)d_in[12];
    const float* Ws2  = (const float*)d_in[13];
    const float* bs2  = (const float*)d_in[14];

    const int N  = in_sizes[0] / 27;
    const int E  = in_sizes[1] / 2;
    const int ET = E + N;
    const int NB = (N + 255) / 256;

    char* ws = (char*)d_ws;
    auto alloc = [&](size_t bytes) -> void* {
        void* p = (void*)ws;
        ws += (bytes + 255) / 256 * 256;
        return p;
    };
    int*      rowptr  = (int*)     alloc((size_t)(N + 1) * 4);
    int*      colsrc  = (int*)     alloc((size_t)ET * 4);
    unsigned* pairs   = (unsigned*)alloc((size_t)ET * 4);
    __half*   xp      = (__half*)  alloc((size_t)N * 64);         // [N][32] fp16
    char*     gbuf    = (char*)    alloc((size_t)N * 512);        // G1 f32[N][128] / G2 fp16[N][256]
    __half*   hm16    = (__half*)  alloc((size_t)N * 128);        // [N][64] fp16
    float*    asrc    = (float*)   alloc((size_t)N * 4 * 4);
    float*    adst    = (float*)   alloc((size_t)N * 4 * 4);
    int*      bucket_cnt    = (int*) alloc(256 * 4);
    int*      bucket_cursor = (int*) alloc(256 * 4);   // contiguous with bucket_cnt
    short*    w1p     = (short*)   alloc(64 * 136 * 2);
    short*    w2p     = (short*)   alloc(64 * 264 * 2);
    short*    s1hi    = (short*)   alloc(64 * 72 * 2);
    short*    s1lo    = (short*)   alloc(64 * 72 * 2);
    float*    d1p     = (float*)   alloc(64 * 4);
    float*    hat2s   = (float*)   alloc(256 * 4);
    float*    hat2d   = (float*)   alloc(256 * 4);

    const int nblk = (N + 63) / 64;
    const int hblk = (ET + 2047) / 2048;
    const int XBP  = 512;

    (void)hipMemsetAsync(bucket_cnt, 0, 512 * 4, stream);
    prep_hist_kernel<<<256 + hblk + XBP, 256, 0, stream>>>(
        W1, W2, Ws1, bs1, donor, as1, ad1, as2, ad2, x,
        w1p, w2p, s1hi, s1lo, d1p, hat2s, hat2d,
        xp, asrc, adst, ei, E, N, NB, bucket_cnt, hblk, XBP);
    coarse_scatter_kernel<<<hblk, 256, 0, stream>>>(ei, E, N, NB, bucket_cnt, bucket_cursor, pairs);
    fine_sort_kernel<<<NB, 256, 0, stream>>>(pairs, bucket_cnt, NB, colsrc, rowptr, N, ET);
    aggregate_kernel<1><<<(N + 7) / 8, 256, 0, stream>>>(
        rowptr, colsrc, (const char*)xp, asrc, adst, gbuf, N);
    t1post_kernel<<<nblk, 256, 0, stream>>>(
        (const float*)gbuf, w1p, b1, hat2s, hat2d, hm16, asrc, adst, N);
    aggregate_kernel<2><<<(N + 7) / 8, 256, 0, stream>>>(
        rowptr, colsrc, (const char*)hm16, asrc, adst, gbuf, N);
    t2post_scorer_kernel<<<nblk, 256, 0, stream>>>(
        gbuf, w2p, b2, s1hi, s1lo, d1p, Ws2, bs2, (float*)d_out, N);
}

// Round 12
// 232.583 us; speedup vs baseline: 1.0380x; 1.0380x over previous
//
#include <hip/hip_runtime.h>
#include <hip/hip_fp16.h>
#include <cmath>

#define NEG 0.2f

typedef __attribute__((ext_vector_type(8))) short short8;
typedef __attribute__((ext_vector_type(4))) float f32x4;
typedef __fp16 half2_t __attribute__((ext_vector_type(2)));

__device__ __forceinline__ float leaky(float v){ return v > 0.f ? v : NEG * v; }

__device__ __forceinline__ short bf16_rne(float f){
    unsigned u = __float_as_uint(f);
    unsigned r = u + 0x7fffu + ((u >> 16) & 1u);
    return (short)(r >> 16);
}
__device__ __forceinline__ float bf16_to_f(short s){
    return __uint_as_float(((unsigned)(unsigned short)s) << 16);
}
__device__ __forceinline__ half2_t bc16(unsigned u){ return __builtin_bit_cast(half2_t, u); }
__device__ __forceinline__ unsigned packh2(float a, float b){
    __half ha = __float2half(a), hb = __float2half(b);   // RNE
    return (unsigned)__builtin_bit_cast(unsigned short, ha)
         | ((unsigned)__builtin_bit_cast(unsigned short, hb) << 16);
}

// block-wide exclusive scan of one int per thread (256 threads)
__device__ __forceinline__ int block_excl_scan(int v, int* ws4){
    int tid = threadIdx.x, lane = tid & 63, wv = tid >> 6;
    int incl = v;
    #pragma unroll
    for (int off = 1; off < 64; off <<= 1){
        int t = __shfl_up(incl, off);
        if (lane >= off) incl += t;
    }
    if (lane == 63) ws4[wv] = incl;
    __syncthreads();
    int add = 0;
    for (int w = 0; w < wv; ++w) add += ws4[w];
    return incl - v + add;
}

// ---------------- prep (+ edge histogram + xp pack/alpha blocks) ----------------
// AGGREGATE-FIRST (r9, verified): gathers act on RAW features; dense GEMMs after.

__global__ __launch_bounds__(256) void prep_hist_kernel(
    const float* __restrict__ W1, const float* __restrict__ W2,
    const float* __restrict__ Ws1, const float* __restrict__ bs1,
    const float* __restrict__ donor,
    const float* __restrict__ as1, const float* __restrict__ ad1,
    const float* __restrict__ as2, const float* __restrict__ ad2,
    const float* __restrict__ x,
    short* __restrict__ w1p, short* __restrict__ w2p,
    short* __restrict__ s1hi, short* __restrict__ s1lo, float* __restrict__ d1p,
    float* __restrict__ hat2s, float* __restrict__ hat2d,
    __half* __restrict__ xp, float* __restrict__ asrc, float* __restrict__ adst,
    const int* __restrict__ ei, int E, int N, int NB, int* __restrict__ bucket_cnt,
    int hblk, int XBP)
{
    int b = (int)blockIdx.x;
    if (b < 256){
        int t = b * 256 + threadIdx.x;
        int T = 256 * 256;
        for (int i = t; i < 64 * 136; i += T){
            int c = i / 136, kk = i % 136; short v = 0;
            if (kk < 128){ int h = kk >> 5, k = kk & 31;
                if (k < 27) v = bf16_rne(W1[(size_t)k * 256 + h * 64 + c] * 0.25f); }
            w1p[i] = v;
        }
        for (int i = t; i < 64 * 264; i += T){
            int c = i / 264, kk = i % 264; short v = 0;
            if (kk < 256){ int h = kk >> 6, k = kk & 63;
                v = bf16_rne(W2[(size_t)k * 256 + h * 64 + c] * 0.25f); }
            w2p[i] = v;
        }
        for (int i = t; i < 64 * 72; i += T){
            int nn = i / 72, k = i % 72;
            float v = (k < 64) ? Ws1[(size_t)k * 64 + nn] : 0.f;
            short hi = bf16_rne(v);
            s1hi[i] = hi; s1lo[i] = bf16_rne(v - bf16_to_f(hi));
        }
        if (t < 64){
            float s = bs1[t];
            for (int k = 0; k < 32; ++k) s = fmaf(donor[k], Ws1[(size_t)(64 + k) * 64 + t], s);
            d1p[t] = s;
        }
        if (t < 256){
            int h = t >> 6, k = t & 63;
            float s = 0.f, d = 0.f;
            for (int c = 0; c < 64; ++c){
                float w = W2[(size_t)k * 256 + h * 64 + c];
                s = fmaf(w, as2[h * 64 + c], s);
                d = fmaf(w, ad2[h * 64 + c], d);
            }
            hat2s[t] = s; hat2d[t] = d;
        }
    } else if (b < 256 + hblk){
        __shared__ int lh[256];
        int tid = threadIdx.x;
        int ET = E + N;
        int ebase = (b - 256) * 2048;
        lh[tid] = 0;
        __syncthreads();
        #pragma unroll
        for (int j = 0; j < 8; ++j){
            int e = ebase + j * 256 + tid;
            if (e < ET){
                int d = (e < E) ? ei[E + e] : (e - E);
                atomicAdd(&lh[d >> 8], 1);
            }
        }
        __syncthreads();
        if (tid < NB && lh[tid]) atomicAdd(&bucket_cnt[tid], lh[tid]);
    } else {
        // pack + layer-1 alphas; hat1 computed locally (no cross-block dep)
        __shared__ float h1s[128], h1d[128];
        int tid = threadIdx.x;
        if (tid < 128){
            int h = tid >> 5, k = tid & 31;
            float s = 0.f, d = 0.f;
            if (k < 27)
                for (int c = 0; c < 64; ++c){
                    float w = W1[(size_t)k * 256 + h * 64 + c];
                    s = fmaf(w, as1[h * 64 + c], s);
                    d = fmaf(w, ad1[h * 64 + c], d);
                }
            h1s[tid] = s; h1d[tid] = d;
        }
        __syncthreads();
        int pb = b - 256 - hblk;
        int t0 = pb * 256 + tid, T = XBP * 256;
        for (int i = t0; i < N * 32; i += T){
            int nn = i >> 5, k = i & 31;
            xp[i] = __float2half((k < 27) ? x[(size_t)nn * 27 + k] : 0.f);
        }
        for (int nn = t0; nn < N; nn += T){
            float xr[27];
            #pragma unroll
            for (int k = 0; k < 27; ++k) xr[k] = x[(size_t)nn * 27 + k];
            #pragma unroll
            for (int h = 0; h < 4; ++h){
                float s = 0.f, d = 0.f;
                #pragma unroll
                for (int k = 0; k < 27; ++k){
                    s = fmaf(xr[k], h1s[h * 32 + k], s);
                    d = fmaf(xr[k], h1d[h * 32 + k], d);
                }
                asrc[nn * 4 + h] = s;
                adst[nn * 4 + h] = d;
            }
        }
    }
}

// ---------------- coarse scatter (self-scan, packed uint32 pairs) ----------------

__global__ __launch_bounds__(256) void coarse_scatter_kernel(
    const int* __restrict__ ei, int E, int N, int NB,
    const int* __restrict__ bucket_cnt, int* __restrict__ bucket_cursor,
    unsigned* __restrict__ pairs)
{
    __shared__ int ws4[4];
    __shared__ int gbase[256];
    __shared__ int lh[256];
    __shared__ int gb[256];
    int tid = threadIdx.x;
    int ET = E + N;
    {
        int v = (tid < NB) ? bucket_cnt[tid] : 0;
        gbase[tid] = block_excl_scan(v, ws4);
    }
    lh[tid] = 0;
    __syncthreads();
    int ebase = blockIdx.x * 2048;
    int d[8], s[8], r[8];
    #pragma unroll
    for (int j = 0; j < 8; ++j){
        int e = ebase + j * 256 + tid;
        d[j] = -1;
        if (e < ET){
            if (e < E){ s[j] = ei[e]; d[j] = ei[E + e]; } else { s[j] = d[j] = e - E; }
            r[j] = atomicAdd(&lh[d[j] >> 8], 1);
        }
    }
    __syncthreads();
    if (tid < NB && lh[tid]) gb[tid] = gbase[tid] + atomicAdd(&bucket_cursor[tid], lh[tid]);
    __syncthreads();
    #pragma unroll
    for (int j = 0; j < 8; ++j){
        if (d[j] >= 0)
            pairs[gb[d[j] >> 8] + r[j]] = ((unsigned)d[j] << 16) | (unsigned)s[j];
    }
}

// ---------------- fine sort (one 256-node bucket per block) ----------------

__global__ __launch_bounds__(256) void fine_sort_kernel(
    const unsigned* __restrict__ pairs, const int* __restrict__ bucket_cnt, int NB,
    int* __restrict__ colsrc, int* __restrict__ rowptr, int N, int ET)
{
    __shared__ int ws4f[4];
    __shared__ int sb[257];
    __shared__ int hist[256];
    __shared__ int cur[256];
    int b = (int)blockIdx.x;
    int tid = threadIdx.x;
    {
        int v = (tid < NB) ? bucket_cnt[tid] : 0;
        int excl = block_excl_scan(v, ws4f);
        sb[tid] = excl;
        if (tid == 255) sb[256] = excl + v;
    }
    hist[tid] = 0;
    __syncthreads();
    int base = sb[b], endb = sb[b + 1];
    int cnt = endb - base;
    int d0 = b << 8;
    for (int i = tid; i < cnt; i += 256){
        unsigned p = pairs[base + i];
        atomicAdd(&hist[(int)(p >> 16) - d0], 1);
    }
    __syncthreads();
    int v = hist[tid];
    int excl = block_excl_scan(v, ws4f);
    cur[tid] = excl;
    if (d0 + tid < N) rowptr[d0 + tid] = base + excl;
    if (b == 0 && tid == 0) rowptr[N] = ET;
    __syncthreads();
    for (int i = tid; i < cnt; i += 256){
        unsigned p = pairs[base + i];
        int r = atomicAdd(&cur[(int)(p >> 16) - d0], 1);
        colsrc[base + r] = (int)(p & 0xFFFFu);
    }
}

// ---------------- aggregation (r0 softmax structure; small payload rows) ----------------
// r12: dual-edge ILP (r0-proven): independent accumulator sets force the
// allocator to keep 2 gathers in flight (r11's VGPR-32 fold limited MLP).
// L=1: xp fp16[N][32] (64B rows); half-split + dual-acc = 4 edges/iter.
//      G1 written fp16 [N][128] (256B rows) — halves agg1 write vs r11.
// L=2: hmid fp16[N][64] (128B rows); 2 edges/iter dual-acc. G2 fp16 [N][256].

template<int L>
__global__ __launch_bounds__(256) void aggregate_kernel(
    const int* __restrict__ rowptr, const int* __restrict__ colsrc,
    const char* __restrict__ pay, const float* __restrict__ asrc,
    const float* __restrict__ adst, char* __restrict__ gout, int N)
{
    constexpr int RS = (L == 1) ? 64 : 128;    // payload row stride (bytes)
    int tid = threadIdx.x;
    int grp = tid >> 5;
    int lane32 = tid & 31;
    int n = blockIdx.x * 8 + grp;
    if (n >= N) return;
    int start = rowptr[n], end = rowptr[n + 1];
    int deg = end - start;
    const float4 ad = *(const float4*)(adst + (size_t)n * 4);

    int src0 = 0;
    float e0 = -1e30f, e1 = -1e30f, e2 = -1e30f, e3 = -1e30f;
    bool v0 = lane32 < deg;
    if (v0){
        src0 = colsrc[start + lane32];
        float4 as = *(const float4*)(asrc + (size_t)src0 * 4);
        e0 = leaky(as.x + ad.x); e1 = leaky(as.y + ad.y);
        e2 = leaky(as.z + ad.z); e3 = leaky(as.w + ad.w);
    }

    float m0, m1, m2, m3, i0, i1, i2, i3, p0, p1, p2, p3;
    if (deg <= 32){
        m0 = e0; m1 = e1; m2 = e2; m3 = e3;
        #pragma unroll
        for (int off = 1; off < 32; off <<= 1){
            m0 = fmaxf(m0, __shfl_xor(m0, off));
            m1 = fmaxf(m1, __shfl_xor(m1, off));
            m2 = fmaxf(m2, __shfl_xor(m2, off));
            m3 = fmaxf(m3, __shfl_xor(m3, off));
        }
        p0 = __expf(e0 - m0);
        p1 = __expf(e1 - m1);
        p2 = __expf(e2 - m2);
        p3 = __expf(e3 - m3);
        float t0 = p0, t1 = p1, t2 = p2, t3 = p3;
        #pragma unroll
        for (int off = 1; off < 32; off <<= 1){
            t0 += __shfl_xor(t0, off);
            t1 += __shfl_xor(t1, off);
            t2 += __shfl_xor(t2, off);
            t3 += __shfl_xor(t3, off);
        }
        i0 = 1.f / t0; i1 = 1.f / t1; i2 = 1.f / t2; i3 = 1.f / t3;
    } else {
        m0 = e0; m1 = e1; m2 = e2; m3 = e3;
        float t0 = v0 ? 1.f : 0.f, t1 = t0, t2 = t0, t3 = t0;
        for (int i = start + 32 + lane32; i < end; i += 32){
            int s = colsrc[i];
            float4 as = *(const float4*)(asrc + (size_t)s * 4);
            float e, nm;
            e = leaky(as.x + ad.x); nm = fmaxf(m0, e); t0 = t0 * __expf(m0 - nm) + __expf(e - nm); m0 = nm;
            e = leaky(as.y + ad.y); nm = fmaxf(m1, e); t1 = t1 * __expf(m1 - nm) + __expf(e - nm); m1 = nm;
            e = leaky(as.z + ad.z); nm = fmaxf(m2, e); t2 = t2 * __expf(m2 - nm) + __expf(e - nm); m2 = nm;
            e = leaky(as.w + ad.w); nm = fmaxf(m3, e); t3 = t3 * __expf(m3 - nm) + __expf(e - nm); m3 = nm;
        }
        #pragma unroll
        for (int off = 1; off < 32; off <<= 1){
            float om, os, nm;
            om = __shfl_xor(m0, off); os = __shfl_xor(t0, off);
            nm = fmaxf(m0, om); t0 = t0 * __expf(m0 - nm) + os * __expf(om - nm); m0 = nm;
            om = __shfl_xor(m1, off); os = __shfl_xor(t1, off);
            nm = fmaxf(m1, om); t1 = t1 * __expf(m1 - nm) + os * __expf(om - nm); m1 = nm;
            om = __shfl_xor(m2, off); os = __shfl_xor(t2, off);
            nm = fmaxf(m2, om); t2 = t2 * __expf(m2 - nm) + os * __expf(om - nm); m2 = nm;
            om = __shfl_xor(m3, off); os = __shfl_xor(t3, off);
            nm = fmaxf(m3, om); t3 = t3 * __expf(m3 - nm) + os * __expf(om - nm); m3 = nm;
        }
        i0 = 1.f / t0; i1 = 1.f / t1; i2 = 1.f / t2; i3 = 1.f / t3;
        p0 = __expf(e0 - m0); p1 = __expf(e1 - m1);
        p2 = __expf(e2 - m2); p3 = __expf(e3 - m3);
    }

    float accx[4] = {0.f, 0.f, 0.f, 0.f};
    float accy[4] = {0.f, 0.f, 0.f, 0.f};
    float accx1[4] = {0.f, 0.f, 0.f, 0.f};
    float accy1[4] = {0.f, 0.f, 0.f, 0.f};
    const int half = lane32 >> 4;
    const int boff = (L == 1) ? (lane32 & 15) * 4 : lane32 * 4;
    bool first = true;
    for (int base = start; base < end; base += 32){
        int cnt = end - base; if (cnt > 32) cnt = 32;
        float w0, w1, w2, w3; int off = 0;
        if (first){
            w0 = p0 * i0; w1 = p1 * i1; w2 = p2 * i2; w3 = p3 * i3;
            off = v0 ? src0 * RS : 0;
        } else {
            w0 = w1 = w2 = w3 = 0.f;
            if (lane32 < cnt){
                int s = colsrc[base + lane32];
                float4 as = *(const float4*)(asrc + (size_t)s * 4);
                w0 = __expf(leaky(as.x + ad.x) - m0) * i0;
                w1 = __expf(leaky(as.y + ad.y) - m1) * i1;
                w2 = __expf(leaky(as.z + ad.z) - m2) * i2;
                w3 = __expf(leaky(as.w + ad.w) - m3) * i3;
                off = s * RS;
            }
        }
        first = false;
        half2_t q01 = __builtin_amdgcn_cvt_pkrtz(w0, w1);
        half2_t q23 = __builtin_amdgcn_cvt_pkrtz(w2, w3);
        int wx = (int)__builtin_bit_cast(unsigned, q01);
        int wy = (int)__builtin_bit_cast(unsigned, q23);

        if (L == 1){
            // 4 edges/iter: half h handles jA=j+h (set0) and jB=j+2+h (set1)
            for (int j = 0; j < cnt; j += 4){
                int jA = j + half, jB = j + 2 + half;
                int selA = (jA < cnt) ? jA : 0;
                int selB = (jB < cnt) ? jB : 0;
                int oA = __shfl(off, selA, 32);
                int oB = __shfl(off, selB, 32);
                unsigned xvA = *(const unsigned*)(pay + oA + boff);
                unsigned xvB = *(const unsigned*)(pay + oB + boff);
                unsigned awA = (unsigned)__shfl(wx, selA, 32);
                unsigned bwA = (unsigned)__shfl(wy, selA, 32);
                unsigned awB = (unsigned)__shfl(wx, selB, 32);
                unsigned bwB = (unsigned)__shfl(wy, selB, 32);
                if (jA >= cnt){ awA = 0u; bwA = 0u; }
                if (jB >= cnt){ awB = 0u; bwB = 0u; }
                half2_t xhA = bc16(xvA), xhB = bc16(xvB);
                float a0 = (float)xhA[0], a1 = (float)xhA[1];
                float b0 = (float)xhB[0], b1 = (float)xhB[1];
                half2_t ahA = bc16(awA), bhA = bc16(bwA);
                half2_t ahB = bc16(awB), bhB = bc16(bwB);
                float fA0 = (float)ahA[0], fA1 = (float)ahA[1], fA2 = (float)bhA[0], fA3 = (float)bhA[1];
                float fB0 = (float)ahB[0], fB1 = (float)ahB[1], fB2 = (float)bhB[0], fB3 = (float)bhB[1];
                accx[0] = fmaf(fA0, a0, accx[0]); accy[0] = fmaf(fA0, a1, accy[0]);
                accx[1] = fmaf(fA1, a0, accx[1]); accy[1] = fmaf(fA1, a1, accy[1]);
                accx[2] = fmaf(fA2, a0, accx[2]); accy[2] = fmaf(fA2, a1, accy[2]);
                accx[3] = fmaf(fA3, a0, accx[3]); accy[3] = fmaf(fA3, a1, accy[3]);
                accx1[0] = fmaf(fB0, b0, accx1[0]); accy1[0] = fmaf(fB0, b1, accy1[0]);
                accx1[1] = fmaf(fB1, b0, accx1[1]); accy1[1] = fmaf(fB1, b1, accy1[1]);
                accx1[2] = fmaf(fB2, b0, accx1[2]); accy1[2] = fmaf(fB2, b1, accy1[2]);
                accx1[3] = fmaf(fB3, b0, accx1[3]); accy1[3] = fmaf(fB3, b1, accy1[3]);
            }
        } else {
            int j = 0;
            for (; j + 2 <= cnt; j += 2){
                int o0 = __shfl(off, j, 32);
                int o1 = __shfl(off, j + 1, 32);
                unsigned hv0 = *(const unsigned*)(pay + o0 + boff);
                unsigned hv1 = *(const unsigned*)(pay + o1 + boff);
                unsigned aw0 = (unsigned)__shfl(wx, j, 32);
                unsigned bw0 = (unsigned)__shfl(wy, j, 32);
                unsigned aw1 = (unsigned)__shfl(wx, j + 1, 32);
                unsigned bw1 = (unsigned)__shfl(wy, j + 1, 32);
                half2_t hh0 = bc16(hv0), hh1 = bc16(hv1);
                float c00 = (float)hh0[0], c01 = (float)hh0[1];
                float c10 = (float)hh1[0], c11 = (float)hh1[1];
                half2_t ah0 = bc16(aw0), bh0 = bc16(bw0);
                half2_t ah1 = bc16(aw1), bh1 = bc16(bw1);
                float f00 = (float)ah0[0], f01 = (float)ah0[1], f02 = (float)bh0[0], f03 = (float)bh0[1];
                float f10 = (float)ah1[0], f11 = (float)ah1[1], f12 = (float)bh1[0], f13 = (float)bh1[1];
                accx[0] = fmaf(f00, c00, accx[0]); accy[0] = fmaf(f00, c01, accy[0]);
                accx[1] = fmaf(f01, c00, accx[1]); accy[1] = fmaf(f01, c01, accy[1]);
                accx[2] = fmaf(f02, c00, accx[2]); accy[2] = fmaf(f02, c01, accy[2]);
                accx[3] = fmaf(f03, c00, accx[3]); accy[3] = fmaf(f03, c01, accy[3]);
                accx1[0] = fmaf(f10, c10, accx1[0]); accy1[0] = fmaf(f10, c11, accy1[0]);
                accx1[1] = fmaf(f11, c10, accx1[1]); accy1[1] = fmaf(f11, c11, accy1[1]);
                accx1[2] = fmaf(f12, c10, accx1[2]); accy1[2] = fmaf(f12, c11, accy1[2]);
                accx1[3] = fmaf(f13, c10, accx1[3]); accy1[3] = fmaf(f13, c11, accy1[3]);
            }
            if (j < cnt){
                int o0 = __shfl(off, j, 32);
                unsigned aw0 = (unsigned)__shfl(wx, j, 32);
                unsigned bw0 = (unsigned)__shfl(wy, j, 32);
                unsigned hv0 = *(const unsigned*)(pay + o0 + boff);
                half2_t hh0 = bc16(hv0);
                float c00 = (float)hh0[0], c01 = (float)hh0[1];
                half2_t ah0 = bc16(aw0), bh0 = bc16(bw0);
                float f00 = (float)ah0[0], f01 = (float)ah0[1], f02 = (float)bh0[0], f03 = (float)bh0[1];
                accx[0] = fmaf(f00, c00, accx[0]); accy[0] = fmaf(f00, c01, accy[0]);
                accx[1] = fmaf(f01, c00, accx[1]); accy[1] = fmaf(f01, c01, accy[1]);
                accx[2] = fmaf(f02, c00, accx[2]); accy[2] = fmaf(f02, c01, accy[2]);
                accx[3] = fmaf(f03, c00, accx[3]); accy[3] = fmaf(f03, c01, accy[3]);
            }
        }
    }

    #pragma unroll
    for (int h = 0; h < 4; ++h){
        accx[h] += accx1[h];
        accy[h] += accy1[h];
    }

    if (L == 1){
        #pragma unroll
        for (int h = 0; h < 4; ++h){
            accx[h] += __shfl_xor(accx[h], 16);
            accy[h] += __shfl_xor(accy[h], 16);
        }
        if (lane32 < 16){
            // G1 fp16 [N][128] (256B rows): lane l holds channels 2l,2l+1 per head
            #pragma unroll
            for (int h = 0; h < 4; ++h){
                unsigned u = packh2(accx[h], accy[h]);
                *(unsigned*)(gout + (size_t)n * 256 + h * 64 + lane32 * 4) = u;
            }
        }
    } else {
        #pragma unroll
        for (int h = 0; h < 4; ++h){
            unsigned u = packh2(accx[h], accy[h]);
            *(unsigned*)(gout + (size_t)n * 512 + h * 128 + lane32 * 4) = u;
        }
    }
}

// ---------------- t1post: hmid = elu(G1 @ W1p + b1), + layer-2 alphas ----------------
// G1 fp16 [N][128] DIRECT reads (256B rows); B = w1p bf16 in LDS; bf16x2 A split.

__global__ __launch_bounds__(256) void t1post_kernel(
    const char* __restrict__ G1, const short* __restrict__ w1p, const float* __restrict__ b1,
    const float* __restrict__ hat2s, const float* __restrict__ hat2d,
    __half* __restrict__ hm16, float* __restrict__ asrc, float* __restrict__ adst, int N)
{
    constexpr int WP = 136;
    __shared__ short wt[64 * WP];
    const int tid = threadIdx.x;
    const int n0 = blockIdx.x * 64;
    const int wv = tid >> 6, lane = tid & 63;
    const int quad = lane >> 4, ln = lane & 15;
    const int myrow = wv * 16 + ln;
    const int nme = n0 + myrow;

    {
        const short8* g = (const short8*)w1p;
        short8* l = (short8*)wt;
        for (int t = tid; t < 64 * WP / 8; t += 256) l[t] = g[t];
    }
    __syncthreads();

    f32x4 acc[4];
    #pragma unroll
    for (int i = 0; i < 4; ++i) acc[i] = (f32x4){0.f, 0.f, 0.f, 0.f};

    #pragma unroll
    for (int ks = 0; ks < 4; ++ks){
        const int k0 = ks * 32 + quad * 8;
        uint4 u = make_uint4(0u, 0u, 0u, 0u);
        if (nme < N)
            u = *(const uint4*)(G1 + (size_t)nme * 256 + (size_t)k0 * 2);
        half2_t h0 = bc16(u.x), h1 = bc16(u.y), h2 = bc16(u.z), h3 = bc16(u.w);
        float fa[8] = {(float)h0[0], (float)h0[1], (float)h1[0], (float)h1[1],
                       (float)h2[0], (float)h2[1], (float)h3[0], (float)h3[1]};
        short8 ahi, alo;
        #pragma unroll
        for (int e = 0; e < 8; ++e){
            short hi = bf16_rne(fa[e]);
            ahi[e] = hi;
            alo[e] = bf16_rne(fa[e] - bf16_to_f(hi));
        }
        #pragma unroll
        for (int nt = 0; nt < 4; ++nt){
            short8 bhi = *(const short8*)(wt + (nt * 16 + ln) * WP + k0);
            acc[nt] = __builtin_amdgcn_mfma_f32_16x16x32_bf16(ahi, bhi, acc[nt], 0, 0, 0);
            acc[nt] = __builtin_amdgcn_mfma_f32_16x16x32_bf16(alo, bhi, acc[nt], 0, 0, 0);
        }
    }

    float b1v[4], hs[4][4], hd[4][4];
    #pragma unroll
    for (int nt = 0; nt < 4; ++nt) b1v[nt] = b1[nt * 16 + ln];
    #pragma unroll
    for (int h = 0; h < 4; ++h)
        #pragma unroll
        for (int nt = 0; nt < 4; ++nt){
            hs[h][nt] = hat2s[h * 64 + nt * 16 + ln];
            hd[h][nt] = hat2d[h * 64 + nt * 16 + ln];
        }

    #pragma unroll
    for (int r = 0; r < 4; ++r){
        int n = n0 + wv * 16 + quad * 4 + r;
        float ev[4];
        #pragma unroll
        for (int nt = 0; nt < 4; ++nt){
            float v = acc[nt][r] + b1v[nt];
            v = (v > 0.f) ? v : expm1f(v);
            ev[nt] = v;
        }
        if (n < N){
            #pragma unroll
            for (int nt = 0; nt < 4; ++nt)
                hm16[(size_t)n * 64 + nt * 16 + ln] = __float2half(ev[nt]);
        }
        #pragma unroll
        for (int h = 0; h < 4; ++h){
            float ps = 0.f, pd = 0.f;
            #pragma unroll
            for (int nt = 0; nt < 4; ++nt){
                ps = fmaf(ev[nt], hs[h][nt], ps);
                pd = fmaf(ev[nt], hd[h][nt], pd);
            }
            #pragma unroll
            for (int off = 1; off < 16; off <<= 1){
                ps += __shfl_xor(ps, off);
                pd += __shfl_xor(pd, off);
            }
            if (ln == 0 && n < N){
                asrc[n * 4 + h] = ps;
                adst[n * 4 + h] = pd;
            }
        }
    }
}

// ---------------- t2post+scorer fused: elu(G2@W2p+b2) -> LDS -> scorer MFMA ----------------

__global__ __launch_bounds__(256) void t2post_scorer_kernel(
    const char* __restrict__ G2, const short* __restrict__ w2p, const float* __restrict__ b2,
    const short* __restrict__ s1hi, const short* __restrict__ s1lo,
    const float* __restrict__ d1p, const float* __restrict__ Ws2, const float* __restrict__ bs2,
    float* __restrict__ out, int N)
{
    constexpr int WP2 = 264;
    constexpr int WPS = 72;
    __shared__ __align__(16) char S[64 * 68 * 4 + 2 * 64 * WPS * 2];   // 35840 B
    const int tid = threadIdx.x;
    const int n0 = blockIdx.x * 64;
    const int wv = tid >> 6, lane = tid & 63;
    const int quad = lane >> 4, ln = lane & 15;
    const int myrow = wv * 16 + ln;
    const int nme = n0 + myrow;

    // ---- phase A: G2 @ W2p
    short* wt = (short*)S;
    {
        const short8* g = (const short8*)w2p;
        short8* l = (short8*)wt;
        for (int t = tid; t < 64 * WP2 / 8; t += 256) l[t] = g[t];
    }
    __syncthreads();

    f32x4 acc[4];
    #pragma unroll
    for (int i = 0; i < 4; ++i) acc[i] = (f32x4){0.f, 0.f, 0.f, 0.f};

    #pragma unroll
    for (int ks = 0; ks < 8; ++ks){
        const int k0 = ks * 32 + quad * 8;
        uint4 u = make_uint4(0u, 0u, 0u, 0u);
        if (nme < N)
            u = *(const uint4*)(G2 + (size_t)nme * 512 + (size_t)k0 * 2);
        half2_t h0 = bc16(u.x), h1 = bc16(u.y), h2 = bc16(u.z), h3 = bc16(u.w);
        float fa[8] = {(float)h0[0], (float)h0[1], (float)h1[0], (float)h1[1],
                       (float)h2[0], (float)h2[1], (float)h3[0], (float)h3[1]};
        short8 ahi, alo;
        #pragma unroll
        for (int e = 0; e < 8; ++e){
            short hi = bf16_rne(fa[e]);
            ahi[e] = hi;
            alo[e] = bf16_rne(fa[e] - bf16_to_f(hi));
        }
        #pragma unroll
        for (int nt = 0; nt < 4; ++nt){
            short8 bhi = *(const short8*)(wt + (nt * 16 + ln) * WP2 + k0);
            acc[nt] = __builtin_amdgcn_mfma_f32_16x16x32_bf16(ahi, bhi, acc[nt], 0, 0, 0);
            acc[nt] = __builtin_amdgcn_mfma_f32_16x16x32_bf16(alo, bhi, acc[nt], 0, 0, 0);
        }
    }

    float b2v[4];
    #pragma unroll
    for (int nt = 0; nt < 4; ++nt) b2v[nt] = b2[nt * 16 + ln];

    // ---- LDS overlay swap: wt no longer needed
    __syncthreads();
    float* hm  = (float*)S;                       // [64][68]
    short* whi = (short*)(S + 64 * 68 * 4);
    short* wlo = whi + 64 * WPS;

    #pragma unroll
    for (int r = 0; r < 4; ++r){
        int row = wv * 16 + quad * 4 + r;
        #pragma unroll
        for (int nt = 0; nt < 4; ++nt){
            float v = acc[nt][r] + b2v[nt];
            v = (v > 0.f) ? v : expm1f(v);
            hm[row * 68 + nt * 16 + ln] = v;
        }
    }
    {
        const short8* ghi = (const short8*)s1hi;
        const short8* glo = (const short8*)s1lo;
        short8* lhi = (short8*)whi;
        short8* llo = (short8*)wlo;
        for (int t = tid; t < 64 * WPS / 8; t += 256){ lhi[t] = ghi[t]; llo[t] = glo[t]; }
    }
    __syncthreads();

    // ---- phase B: scorer
    f32x4 acc2[4];
    #pragma unroll
    for (int i = 0; i < 4; ++i) acc2[i] = (f32x4){0.f, 0.f, 0.f, 0.f};

    #pragma unroll
    for (int ks = 0; ks < 2; ++ks){
        const int k0 = ks * 32 + quad * 8;
        short8 ahi, alo;
        #pragma unroll
        for (int e = 0; e < 8; ++e){
            float v = hm[myrow * 68 + k0 + e];
            short hi = bf16_rne(v);
            ahi[e] = hi;
            alo[e] = bf16_rne(v - bf16_to_f(hi));
        }
        #pragma unroll
        for (int nt = 0; nt < 4; ++nt){
            short8 bhi = *(const short8*)(whi + (nt * 16 + ln) * WPS + k0);
            short8 blo = *(const short8*)(wlo + (nt * 16 + ln) * WPS + k0);
            acc2[nt] = __builtin_amdgcn_mfma_f32_16x16x32_bf16(ahi, bhi, acc2[nt], 0, 0, 0);
            acc2[nt] = __builtin_amdgcn_mfma_f32_16x16x32_bf16(alo, bhi, acc2[nt], 0, 0, 0);
            acc2[nt] = __builtin_amdgcn_mfma_f32_16x16x32_bf16(ahi, blo, acc2[nt], 0, 0, 0);
        }
    }

    float d1v[4], w2v[4];
    #pragma unroll
    for (int nt = 0; nt < 4; ++nt){
        d1v[nt] = d1p[nt * 16 + ln];
        w2v[nt] = Ws2[nt * 16 + ln];
    }
    float bsv = bs2[0];
    #pragma unroll
    for (int r = 0; r < 4; ++r){
        float t = 0.f;
        #pragma unroll
        for (int nt = 0; nt < 4; ++nt)
            t = fmaf(fmaxf(acc2[nt][r] + d1v[nt], 0.f), w2v[nt], t);
        #pragma unroll
        for (int off = 1; off < 16; off <<= 1) t += __shfl_xor(t, off);
        if (ln == 0){
            int n = n0 + wv * 16 + quad * 4 + r;
            if (n < N) out[n] = t + bsv;
        }
    }
}

// ---------------- launch ----------------

extern "C" void kernel_launch(void* const* d_in, const int* in_sizes, int n_in,
                              void* d_out, int out_size, void* d_ws, size_t ws_size,
                              hipStream_t stream)
{
    const float* x    = (const float*)d_in[0];
    const int*   ei   = (const int*)  d_in[1];
    const float* donor= (const float*)d_in[2];
    const float* W1   = (const float*)d_in[3];
    const float* as1  = (const float*)d_in[4];
    const float* ad1  = (const float*)d_in[5];
    const float* b1   = (const float*)d_in[6];
    const float* W2   = (const float*)d_in[7];
    const float* as2  = (const float*)d_in[8];
    const float* ad2  = (const float*)d_in[9];
    const float* b2   = (const float*)d_in[10];
    const float* Ws1  = (const float*)d_in[11];
    const float* bs1  = (const float*)d_in[12];
    const float* Ws2  = (const float*)d_in[13];
    const float* bs2  = (const float*)d_in[14];

    const int N  = in_sizes[0] / 27;
    const int E  = in_sizes[1] / 2;
    const int ET = E + N;
    const int NB = (N + 255) / 256;

    char* ws = (char*)d_ws;
    auto alloc = [&](size_t bytes) -> void* {
        void* p = (void*)ws;
        ws += (bytes + 255) / 256 * 256;
        return p;
    };
    int*      rowptr  = (int*)     alloc((size_t)(N + 1) * 4);
    int*      colsrc  = (int*)     alloc((size_t)ET * 4);
    unsigned* pairs   = (unsigned*)alloc((size_t)ET * 4);
    __half*   xp      = (__half*)  alloc((size_t)N * 64);         // [N][32] fp16
    char*     gbuf    = (char*)    alloc((size_t)N * 512);        // G1 fp16[N][128] / G2 fp16[N][256]
    __half*   hm16    = (__half*)  alloc((size_t)N * 128);        // [N][64] fp16
    float*    asrc    = (float*)   alloc((size_t)N * 4 * 4);
    float*    adst    = (float*)   alloc((size_t)N * 4 * 4);
    int*      bucket_cnt    = (int*) alloc(256 * 4);
    int*      bucket_cursor = (int*) alloc(256 * 4);   // contiguous with bucket_cnt
    short*    w1p     = (short*)   alloc(64 * 136 * 2);
    short*    w2p     = (short*)   alloc(64 * 264 * 2);
    short*    s1hi    = (short*)   alloc(64 * 72 * 2);
    short*    s1lo    = (short*)   alloc(64 * 72 * 2);
    float*    d1p     = (float*)   alloc(64 * 4);
    float*    hat2s   = (float*)   alloc(256 * 4);
    float*    hat2d   = (float*)   alloc(256 * 4);

    const int nblk = (N + 63) / 64;
    const int hblk = (ET + 2047) / 2048;
    const int XBP  = 512;

    (void)hipMemsetAsync(bucket_cnt, 0, 512 * 4, stream);
    prep_hist_kernel<<<256 + hblk + XBP, 256, 0, stream>>>(
        W1, W2, Ws1, bs1, donor, as1, ad1, as2, ad2, x,
        w1p, w2p, s1hi, s1lo, d1p, hat2s, hat2d,
        xp, asrc, adst, ei, E, N, NB, bucket_cnt, hblk, XBP);
    coarse_scatter_kernel<<<hblk, 256, 0, stream>>>(ei, E, N, NB, bucket_cnt, bucket_cursor, pairs);
    fine_sort_kernel<<<NB, 256, 0, stream>>>(pairs, bucket_cnt, NB, colsrc, rowptr, N, ET);
    aggregate_kernel<1><<<(N + 7) / 8, 256, 0, stream>>>(
        rowptr, colsrc, (const char*)xp, asrc, adst, gbuf, N);
    t1post_kernel<<<nblk, 256, 0, stream>>>(
        gbuf, w1p, b1, hat2s, hat2d, hm16, asrc, adst, N);
    aggregate_kernel<2><<<(N + 7) / 8, 256, 0, stream>>>(
        rowptr, colsrc, (const char*)hm16, asrc, adst, gbuf, N);
    t2post_scorer_kernel<<<nblk, 256, 0, stream>>>(
        gbuf, w2p, b2, s1hi, s1lo, d1p, Ws2, bs2, (float*)d_out, N);
}